// Round 6
// baseline (391.829 us; speedup 1.0000x reference)
//
#include <hip/hip_runtime.h>
#include <math.h>

#define D_    64
#define K_    1024
#define N_    131072
#define HW_   4096
#define NTD   256          // threads per dist block (1 row each)
#define KSPL  2            // K split across blocks
#define KHALF (K_ / KSPL)  // 512 codes per block

typedef unsigned long long ull;

// ---- init: packed argmin slots to +inf, hist=0, e2g, ssqd ----
__global__ __launch_bounds__(256)
void vq_init(const float* __restrict__ emb, ull* __restrict__ packed,
             int* __restrict__ hist, double* __restrict__ ssqd,
             float* __restrict__ e2g) {
    int t = blockIdx.x * 256 + threadIdx.x;
    if (t < N_) packed[t] = 0xFFFFFFFFFFFFFFFFull;
    if (t < K_) {
        hist[t] = 0;
        float s = 0.0f;
        const float* e = emb + (size_t)t * D_;
        #pragma unroll
        for (int d = 0; d < D_; ++d) s = fmaf(e[d], e[d], s);   // ascending d
        e2g[t] = s;
    }
    if (t == 0) *ssqd = 0.0;
}

// ---- distance + argmin: z in registers, e via wave-uniform (scalar) loads ----
__global__ __launch_bounds__(NTD)
void vq_dist(const float* __restrict__ x, const float* __restrict__ emb,
             const float* __restrict__ e2g, ull* __restrict__ packed) {
    const int bid  = blockIdx.x;
    const int half = bid & (KSPL - 1);
    const int rb   = bid >> 1;
    const int row  = rb * NTD + threadIdx.x;     // global latent index n
    const int b    = row >> 12;
    const int hw   = row & (HW_ - 1);
    const float* xr = x + (size_t)b * (D_ * HW_) + hw;

    // z row -> registers (coalesced across lanes for each d)
    float z[D_];
    #pragma unroll
    for (int d = 0; d < D_; ++d) z[d] = xr[(size_t)d * HW_];

    // r2: ascending-d fma chain (bitwise == rounds 1-5)
    float r2 = 0.0f;
    #pragma unroll
    for (int d = 0; d < D_; ++d) r2 = fmaf(z[d], z[d], r2);

    float bd = 3.4e38f;
    int   bk = 0;

    const int k0 = half * KHALF;
    for (int k = k0; k < k0 + KHALF; k += 4) {
        const float* e0 = emb + (size_t)k * D_;      // wave-uniform address
        float dot0 = 0.0f, dot1 = 0.0f, dot2 = 0.0f, dot3 = 0.0f;
        #pragma unroll
        for (int d = 0; d < D_; ++d) {
            const float zd = z[d];
            dot0 = fmaf(zd, e0[d],            dot0);  // ascending-d single chains
            dot1 = fmaf(zd, e0[D_ + d],       dot1);
            dot2 = fmaf(zd, e0[2 * D_ + d],   dot2);
            dot3 = fmaf(zd, e0[3 * D_ + d],   dot3);
        }
        const float di0 = fmaf(-2.0f, dot0, r2 + e2g[k + 0]);
        const float di1 = fmaf(-2.0f, dot1, r2 + e2g[k + 1]);
        const float di2 = fmaf(-2.0f, dot2, r2 + e2g[k + 2]);
        const float di3 = fmaf(-2.0f, dot3, r2 + e2g[k + 3]);
        if (di0 < bd) { bd = di0; bk = k + 0; }      // strict <, ascending k
        if (di1 < bd) { bd = di1; bk = k + 1; }
        if (di2 < bd) { bd = di2; bk = k + 2; }
        if (di3 < bd) { bd = di3; bk = k + 3; }
    }

    // merge across K-split halves; dist > 0 so float bit order == value order;
    // equal dist -> lower k wins (low 32 bits), matching sequential first-min.
    ull p = ((ull)__float_as_uint(bd) << 32) | (unsigned int)bk;
    atomicMin(&packed[row], p);
}

// ---- apply: gather winner, write z_q (straight-through), hist, ssq ----
__global__ __launch_bounds__(256)
void vq_apply(const float* __restrict__ x, const float* __restrict__ emb,
              const ull* __restrict__ packed, float* __restrict__ zq_out,
              int* __restrict__ hist, double* __restrict__ ssqd) {
    const int row = blockIdx.x * 256 + threadIdx.x;
    const int b   = row >> 12;
    const int hw  = row & (HW_ - 1);
    const float* xr   = x      + (size_t)b * (D_ * HW_) + hw;
    float*       outr = zq_out + (size_t)b * (D_ * HW_) + hw;

    const int k = (int)(packed[row] & 0xFFFFFFFFull);
    atomicAdd(&hist[k], 1);

    const float* er = emb + (size_t)k * D_;
    float ls = 0.0f;
    #pragma unroll
    for (int d = 0; d < D_; ++d) {
        float zv = xr[(size_t)d * HW_];
        float e  = er[d];                    // L2-hot gather (emb = 256 KB)
        float t  = e - zv;
        ls = fmaf(t, t, ls);
        outr[(size_t)d * HW_] = zv + t;      // coalesced scalar store
    }

    #pragma unroll
    for (int o = 32; o > 0; o >>= 1) ls += __shfl_down(ls, o, 64);
    if ((threadIdx.x & 63) == 0) atomicAdd(ssqd, (double)ls);
}

__global__ __launch_bounds__(1024)
void vq_final(const int* __restrict__ hist, const double* __restrict__ ssqd,
              float* __restrict__ out_loss, float* __restrict__ out_perp) {
    __shared__ float wred[16];
    int t = threadIdx.x;
    float cnt = (float)hist[t];
    float em  = cnt / (float)N_;
    float s   = em * logf(em + 1e-10f);
    #pragma unroll
    for (int o = 32; o > 0; o >>= 1) s += __shfl_down(s, o, 64);
    if ((t & 63) == 0) wred[t >> 6] = s;
    __syncthreads();
    if (t == 0) {
        float tot = 0.0f;
        for (int w = 0; w < 16; ++w) tot += wred[w];
        *out_perp = expf(-tot);
        float mse = (float)(*ssqd / (double)((size_t)N_ * D_));
        *out_loss = mse + 0.25f * mse;
    }
}

extern "C" void kernel_launch(void* const* d_in, const int* in_sizes, int n_in,
                              void* d_out, int out_size, void* d_ws, size_t ws_size,
                              hipStream_t stream) {
    const float* x   = (const float*)d_in[0];
    const float* emb = (const float*)d_in[1];
    float* out  = (float*)d_out;
    float* loss = out;
    float* zq   = out + 1;
    float* perp = out + 1 + (size_t)N_ * D_;

    ull*    packed = (ull*)d_ws;                                   // 1 MiB
    int*    hist   = (int*)((char*)d_ws + (size_t)N_ * 8);         // 4 KiB
    float*  e2g    = (float*)((char*)hist + K_ * sizeof(int));     // 4 KiB
    double* ssqd   = (double*)((char*)e2g + K_ * sizeof(float));   // 8 B

    vq_init<<<dim3(N_ / 256), dim3(256), 0, stream>>>(emb, packed, hist, ssqd, e2g);
    vq_dist<<<dim3((N_ / NTD) * KSPL), dim3(NTD), 0, stream>>>(x, emb, e2g, packed);
    vq_apply<<<dim3(N_ / 256), dim3(256), 0, stream>>>(x, emb, packed, zq, hist, ssqd);
    vq_final<<<dim3(1), dim3(1024), 0, stream>>>(hist, ssqd, loss, perp);
}

// Round 7
// 387.472 us; speedup vs baseline: 1.0112x; 1.0112x over previous
//
#include <hip/hip_runtime.h>
#include <math.h>

#define D_    64
#define K_    1024
#define N_    131072
#define HW_   4096
#define NTD   256          // threads per dist block (1 row each)
#define KSPL  2            // K split across blocks
#define KHALF (K_ / KSPL)  // 512 codes per block

typedef unsigned long long ull;

// ---- init: packed argmin slots to +inf, hist=0, e2g, ssqd ----
__global__ __launch_bounds__(256)
void vq_init(const float* __restrict__ emb, ull* __restrict__ packed,
             int* __restrict__ hist, double* __restrict__ ssqd,
             float* __restrict__ e2g) {
    int t = blockIdx.x * 256 + threadIdx.x;
    if (t < N_) packed[t] = 0xFFFFFFFFFFFFFFFFull;
    if (t < K_) {
        hist[t] = 0;
        float s = 0.0f;
        const float* e = emb + (size_t)t * D_;
        #pragma unroll
        for (int d = 0; d < D_; ++d) s = fmaf(e[d], e[d], s);   // ascending d
        e2g[t] = s;
    }
    if (t == 0) *ssqd = 0.0;
}

// z row in 16 NAMED float4s (named locals cannot be demoted to scratch).
#define LD4(zq, d0) \
    zq.x = xr[(size_t)((d0) + 0) * HW_]; \
    zq.y = xr[(size_t)((d0) + 1) * HW_]; \
    zq.z = xr[(size_t)((d0) + 2) * HW_]; \
    zq.w = xr[(size_t)((d0) + 3) * HW_];

#define R24(zq) \
    r2 = fmaf(zq.x, zq.x, r2); r2 = fmaf(zq.y, zq.y, r2); \
    r2 = fmaf(zq.z, zq.z, r2); r2 = fmaf(zq.w, zq.w, r2);

#define F4(dv, zq, o) \
    dv = fmaf(zq.x, ep[(o) + 0], dv); dv = fmaf(zq.y, ep[(o) + 1], dv); \
    dv = fmaf(zq.z, ep[(o) + 2], dv); dv = fmaf(zq.w, ep[(o) + 3], dv);

#define DOT64(dv, base) { \
    const float* ep = e0 + (base); \
    F4(dv, z0,  0)  F4(dv, z1,  4)  F4(dv, z2,  8)  F4(dv, z3,  12) \
    F4(dv, z4,  16) F4(dv, z5,  20) F4(dv, z6,  24) F4(dv, z7,  28) \
    F4(dv, z8,  32) F4(dv, z9,  36) F4(dv, z10, 40) F4(dv, z11, 44) \
    F4(dv, z12, 48) F4(dv, z13, 52) F4(dv, z14, 56) F4(dv, z15, 60) }

// ---- distance + argmin: z in registers, e via wave-uniform (scalar) loads ----
__global__ __launch_bounds__(NTD, 4)
void vq_dist(const float* __restrict__ x, const float* __restrict__ emb,
             const float* __restrict__ e2g, ull* __restrict__ packed) {
    const int bid  = blockIdx.x;
    const int half = bid & (KSPL - 1);
    const int rb   = bid >> 1;
    const int row  = rb * NTD + threadIdx.x;     // global latent index n
    const int b    = row >> 12;
    const int hw   = row & (HW_ - 1);
    const float* xr = x + (size_t)b * (D_ * HW_) + hw;

    float4 z0, z1, z2, z3, z4, z5, z6, z7, z8, z9, z10, z11, z12, z13, z14, z15;
    LD4(z0,  0)  LD4(z1,  4)  LD4(z2,  8)  LD4(z3,  12)
    LD4(z4,  16) LD4(z5,  20) LD4(z6,  24) LD4(z7,  28)
    LD4(z8,  32) LD4(z9,  36) LD4(z10, 40) LD4(z11, 44)
    LD4(z12, 48) LD4(z13, 52) LD4(z14, 56) LD4(z15, 60)

    // r2: ascending-d fma chain (bitwise == rounds 1-6)
    float r2 = 0.0f;
    R24(z0)  R24(z1)  R24(z2)  R24(z3)  R24(z4)  R24(z5)  R24(z6)  R24(z7)
    R24(z8)  R24(z9)  R24(z10) R24(z11) R24(z12) R24(z13) R24(z14) R24(z15)

    float bd = 3.4e38f;
    int   bk = 0;

    const int k0 = half * KHALF;
    for (int k = k0; k < k0 + KHALF; k += 4) {
        const float* e0 = emb + (size_t)k * D_;      // wave-uniform address
        float dot0 = 0.0f, dot1 = 0.0f, dot2 = 0.0f, dot3 = 0.0f;
        DOT64(dot0, 0)
        DOT64(dot1, D_)
        DOT64(dot2, 2 * D_)
        DOT64(dot3, 3 * D_)
        const float di0 = fmaf(-2.0f, dot0, r2 + e2g[k + 0]);
        const float di1 = fmaf(-2.0f, dot1, r2 + e2g[k + 1]);
        const float di2 = fmaf(-2.0f, dot2, r2 + e2g[k + 2]);
        const float di3 = fmaf(-2.0f, dot3, r2 + e2g[k + 3]);
        if (di0 < bd) { bd = di0; bk = k + 0; }      // strict <, ascending k
        if (di1 < bd) { bd = di1; bk = k + 1; }
        if (di2 < bd) { bd = di2; bk = k + 2; }
        if (di3 < bd) { bd = di3; bk = k + 3; }
    }

    // merge across K-split halves; dist > 0 so float bit order == value order;
    // equal dist -> lower k wins (low 32 bits), matching sequential first-min.
    ull p = ((ull)__float_as_uint(bd) << 32) | (unsigned int)bk;
    atomicMin(&packed[row], p);
}

// ---- apply: gather winner, write z_q (straight-through), hist, ssq ----
__global__ __launch_bounds__(256)
void vq_apply(const float* __restrict__ x, const float* __restrict__ emb,
              const ull* __restrict__ packed, float* __restrict__ zq_out,
              int* __restrict__ hist, double* __restrict__ ssqd) {
    const int row = blockIdx.x * 256 + threadIdx.x;
    const int b   = row >> 12;
    const int hw  = row & (HW_ - 1);
    const float* xr   = x      + (size_t)b * (D_ * HW_) + hw;
    float*       outr = zq_out + (size_t)b * (D_ * HW_) + hw;

    const int k = (int)(packed[row] & 0xFFFFFFFFull);
    atomicAdd(&hist[k], 1);

    const float* er = emb + (size_t)k * D_;
    float ls = 0.0f;
    #pragma unroll
    for (int d = 0; d < D_; ++d) {
        float zv = xr[(size_t)d * HW_];
        float e  = er[d];                    // L2-hot gather (emb = 256 KB)
        float t  = e - zv;
        ls = fmaf(t, t, ls);
        outr[(size_t)d * HW_] = zv + t;      // coalesced scalar store
    }

    #pragma unroll
    for (int o = 32; o > 0; o >>= 1) ls += __shfl_down(ls, o, 64);
    if ((threadIdx.x & 63) == 0) atomicAdd(ssqd, (double)ls);
}

__global__ __launch_bounds__(1024)
void vq_final(const int* __restrict__ hist, const double* __restrict__ ssqd,
              float* __restrict__ out_loss, float* __restrict__ out_perp) {
    __shared__ float wred[16];
    int t = threadIdx.x;
    float cnt = (float)hist[t];
    float em  = cnt / (float)N_;
    float s   = em * logf(em + 1e-10f);
    #pragma unroll
    for (int o = 32; o > 0; o >>= 1) s += __shfl_down(s, o, 64);
    if ((t & 63) == 0) wred[t >> 6] = s;
    __syncthreads();
    if (t == 0) {
        float tot = 0.0f;
        for (int w = 0; w < 16; ++w) tot += wred[w];
        *out_perp = expf(-tot);
        float mse = (float)(*ssqd / (double)((size_t)N_ * D_));
        *out_loss = mse + 0.25f * mse;
    }
}

extern "C" void kernel_launch(void* const* d_in, const int* in_sizes, int n_in,
                              void* d_out, int out_size, void* d_ws, size_t ws_size,
                              hipStream_t stream) {
    const float* x   = (const float*)d_in[0];
    const float* emb = (const float*)d_in[1];
    float* out  = (float*)d_out;
    float* loss = out;
    float* zq   = out + 1;
    float* perp = out + 1 + (size_t)N_ * D_;

    ull*    packed = (ull*)d_ws;                                   // 1 MiB
    int*    hist   = (int*)((char*)d_ws + (size_t)N_ * 8);         // 4 KiB
    float*  e2g    = (float*)((char*)hist + K_ * sizeof(int));     // 4 KiB
    double* ssqd   = (double*)((char*)e2g + K_ * sizeof(float));   // 8 B

    vq_init<<<dim3(N_ / 256), dim3(256), 0, stream>>>(emb, packed, hist, ssqd, e2g);
    vq_dist<<<dim3((N_ / NTD) * KSPL), dim3(NTD), 0, stream>>>(x, emb, e2g, packed);
    vq_apply<<<dim3(N_ / 256), dim3(256), 0, stream>>>(x, emb, packed, zq, hist, ssqd);
    vq_final<<<dim3(1), dim3(1024), 0, stream>>>(hist, ssqd, loss, perp);
}